// Round 6
// baseline (357.352 us; speedup 1.0000x reference)
//
#include <hip/hip_runtime.h>

namespace {

constexpr int P    = 361;
constexpr int Fd   = 20;
constexpr int BPc  = 256 * P;        // 92416 sites
constexpr int NG   = BPc / 32;       // 2888 site-groups per f
constexpr int GPW  = 2;              // groups per wave-stream (small => many blocks)
constexpr int NSTR = NG / GPW;       // 1444 wave-streams per f
constexpr int GX   = NSTR / 4;       // 361 blocks.x (4 waves/block)

constexpr int OTS = 36;              // out-tile row stride in floats (144B, 16B-aligned)

typedef __bf16 bf16x8 __attribute__((ext_vector_type(8)));
typedef __bf16 bf16x2 __attribute__((ext_vector_type(2)));
typedef float  f32x2v __attribute__((ext_vector_type(2)));
typedef float  f32x16 __attribute__((ext_vector_type(16)));

// native <2 x float> fma (correct whether or not backend packs it)
__device__ __forceinline__ f32x2v vfma2(f32x2v a, f32x2v b, f32x2v c) {
    return __builtin_elementwise_fma(a, b, c);
}

// tanh-form GELU: 0.5x(1+tanh(0.79788456(x+0.044715x^3)))
//   y  = x*(c0 + c0c1*x^2)
//   r  = 1/(exp2(2*log2e*y) + 1)        (= 0.5*(1-tanh(y)))
//   g  = x*(1-r) = fma(-x, r, x)
// Saturates exactly: exp2->inf => r=0 => g=x ; exp2->0 => r=1 => g=0.
__device__ __forceinline__ f32x2v gelu2(f32x2v x) {
    const f32x2v k1  = {0.03567740814183590f, 0.03567740814183590f}; // c0*c1
    const f32x2v k0  = {0.79788456080286536f, 0.79788456080286536f}; // c0
    const f32x2v k2  = {2.88539008177792681f, 2.88539008177792681f}; // 2*log2(e)
    const f32x2v one = {1.0f, 1.0f};
    f32x2v x2 = x * x;
    f32x2v p  = vfma2(x2, k1, k0);
    f32x2v y  = x * p;
    f32x2v w  = y * k2;
    f32x2v e;
    e.x = __builtin_amdgcn_exp2f(w.x);
    e.y = __builtin_amdgcn_exp2f(w.y);
    f32x2v d = e + one;
    f32x2v r;
    r.x = __builtin_amdgcn_rcpf(d.x);
    r.y = __builtin_amdgcn_rcpf(d.y);
    return vfma2(-x, r, x);
}

// (v0,v1) -> packed hi-bf16 word + packed lo-bf16 word, RNE, via v_cvt_pk_bf16_f32
__device__ __forceinline__ void split_pk(float v0, float v1, unsigned& hw, unsigned& lw) {
    f32x2v vv = {v0, v1};
    bf16x2 hv = __builtin_convertvector(vv, bf16x2);
    unsigned hp = __builtin_bit_cast(unsigned, hv);
    float r0 = __builtin_bit_cast(float, hp << 16);
    float r1 = __builtin_bit_cast(float, hp & 0xffff0000u);
    f32x2v rv = {v0 - r0, v1 - r1};
    bf16x2 lv = __builtin_convertvector(rv, bf16x2);
    hw = hp;
    lw = __builtin_bit_cast(unsigned, lv);
}

__device__ __forceinline__ bf16x8 as_bf8(uint4 u) {
    return __builtin_bit_cast(bf16x8, u);
}

// 3-MFMA bf16x3 product: acc += A * B with A = (ah+al) from LDS frags,
// B = (bh+bl) in registers. Drops al*bl (~2^-18 rel).
__device__ __forceinline__ f32x16 mfma3(const uint4* lf, int lane,
                                        uint4 bh, uint4 bl, f32x16 acc) {
    bf16x8 ah = as_bf8(lf[lane]);
    bf16x8 al = as_bf8(lf[64 + lane]);
    acc = __builtin_amdgcn_mfma_f32_32x32x16_bf16(ah, as_bf8(bh), acc, 0, 0, 0);
    acc = __builtin_amdgcn_mfma_f32_32x32x16_bf16(ah, as_bf8(bl), acc, 0, 0, 0);
    acc = __builtin_amdgcn_mfma_f32_32x32x16_bf16(al, as_bf8(bh), acc, 0, 0, 0);
    return acc;
}

// read per-lane bias (accumulator init) from LDS: layout [half*16 + q*4 + e]
// holds bias[row = e + 8q + 4*half], matching C/D row = (r&3)+8*(r>>2)+4*half.
__device__ __forceinline__ f32x16 bias_acc(const float* lb, int half) {
    f32x16 a;
    const float4* p = (const float4*)(lb + half * 16);
#pragma unroll
    for (int q = 0; q < 4; ++q) {
        float4 v = p[q];
        a[4*q+0] = v.x; a[4*q+1] = v.y; a[4*q+2] = v.z; a[4*q+3] = v.w;
    }
    return a;
}

__device__ __forceinline__ void gelu16(f32x16& c) {
#pragma unroll
    for (int i = 0; i < 8; ++i) {
        f32x2v p = {c[2*i], c[2*i+1]};
        p = gelu2(p);
        c[2*i] = p.x; c[2*i+1] = p.y;
    }
}

// C/D-layout (32 feats x 32 sites) -> two B-fragments (k=0..15, k=16..31),
// hi+lo bf16. C/D: lane holds col n=lane&31, rows (r&3)+8*(r>>2)+4*half.
// B-frag: lane holds n=lane&31, k=(lane>>5)*8+j.
// The half exchange is exactly v_permlane32_swap:
//   swap(A,B): A' = {A_lo, B_lo}, B' = {A_hi, B_hi}
//   v.x,v.z = swap(d[4c+0], d[4c+2]); v.y,v.w = swap(d[4c+1], d[4c+3]).
__device__ __forceinline__ void transform_cd(const f32x16 c, uint4* H, uint4* L) {
    unsigned hd[8], ld[8];
#pragma unroll
    for (int q = 0; q < 4; ++q) {
        split_pk(c[4*q+0], c[4*q+1], hd[2*q],   ld[2*q]);
        split_pk(c[4*q+2], c[4*q+3], hd[2*q+1], ld[2*q+1]);
    }
#pragma unroll
    for (int pr = 0; pr < 2; ++pr) {
        unsigned* d = pr ? ld : hd;
#pragma unroll
        for (int cix = 0; cix < 2; ++cix) {
            unsigned a0 = d[4*cix+0], b0 = d[4*cix+2];
            unsigned a1 = d[4*cix+1], b1 = d[4*cix+3];
            asm("v_permlane32_swap_b32 %0, %1" : "+v"(a0), "+v"(b0));
            asm("v_permlane32_swap_b32 %0, %1" : "+v"(a1), "+v"(b1));
            uint4 v;
            v.x = a0; v.y = a1; v.z = b0; v.w = b1;
            (pr ? L : H)[cix] = v;
        }
    }
}

__global__ __launch_bounds__(256, 4) void dcp_mfma_kernel(
    const float* __restrict__ x,
    const float* __restrict__ Wr1, const float* __restrict__ br1,
    const float* __restrict__ Wr2, const float* __restrict__ br2,
    const float* __restrict__ Wr3, const float* __restrict__ br3,
    const float* __restrict__ Wi1, const float* __restrict__ bi1,
    const float* __restrict__ Wi2, const float* __restrict__ bi2,
    const float* __restrict__ Wi3, const float* __restrict__ bi3,
    const float* __restrict__ Wf1, const float* __restrict__ bf1,
    const float* __restrict__ Wf2, const float* __restrict__ bf2,
    float* __restrict__ out)
{
    // 12 weight A-chunks x {hi,lo}: frag fi=2*chunk+prec, per-lane uint4.
    __shared__ uint4 lfrag[24][64];                 // 24576 B
    __shared__ __align__(16) float lbias[6][32];    //   768 B
    __shared__ __align__(16) float l1w[2][2][16];   //   256 B
    // per-wave out-staging tile: 16 sites x 32 feats, row stride OTS floats
    __shared__ __align__(16) float lout[4][16 * OTS]; // 9216 B  => total 34816 B (4 blocks/CU)

    const int f   = blockIdx.y;
    const int tid = threadIdx.x;

    // ---------- setup: stage weight A-fragments (bf16 hi/lo) into LDS ----------
    // A[m][k] = W[f][k0+k][m]; lane l: m=l&31, k=(l>>5)*8+j.
    for (int s = tid; s < 12 * 64; s += 256) {
        const int chunk = s >> 6;
        const int l     = s & 63;
        const int m     = l & 31;
        const int kb    = (l >> 5) * 8;
        const float* base; int k0;
        switch (chunk) {
            case 0:  base = Wr2 + f * 512;  k0 = 0;  break;
            case 1:  base = Wi2 + f * 512;  k0 = 0;  break;
            case 2:  base = Wr3 + f * 1024; k0 = 0;  break;
            case 3:  base = Wr3 + f * 1024; k0 = 16; break;
            case 4:  base = Wi3 + f * 1024; k0 = 0;  break;
            case 5:  base = Wi3 + f * 1024; k0 = 16; break;
            case 6:  base = Wf1 + f * 2048; k0 = 0;  break;
            case 7:  base = Wf1 + f * 2048; k0 = 16; break;
            case 8:  base = Wf1 + f * 2048; k0 = 32; break;
            case 9:  base = Wf1 + f * 2048; k0 = 48; break;
            case 10: base = Wf2 + f * 1024; k0 = 0;  break;
            default: base = Wf2 + f * 1024; k0 = 16; break;
        }
        uint4 hv, lv;
        split_pk(base[(k0 + kb + 0) * 32 + m], base[(k0 + kb + 1) * 32 + m], hv.x, lv.x);
        split_pk(base[(k0 + kb + 2) * 32 + m], base[(k0 + kb + 3) * 32 + m], hv.y, lv.y);
        split_pk(base[(k0 + kb + 4) * 32 + m], base[(k0 + kb + 5) * 32 + m], hv.z, lv.z);
        split_pk(base[(k0 + kb + 6) * 32 + m], base[(k0 + kb + 7) * 32 + m], hv.w, lv.w);
        lfrag[2 * chunk + 0][l] = hv;
        lfrag[2 * chunk + 1][l] = lv;
    }
    // biases, rearranged to C/D reg order per lane-half
    if (tid < 192) {
        const int set = tid >> 5, i = tid & 31;
        const int row = (i & 3) + 8 * ((i >> 2) & 3) + 4 * (i >> 4);
        const float* bp;
        switch (set) {
            case 0: bp = br2; break; case 1: bp = bi2; break;
            case 2: bp = br3; break; case 3: bp = bi3; break;
            case 4: bp = bf1; break; default: bp = bf2; break;
        }
        lbias[set][i] = bp[f * 32 + row];
    }
    // layer-1 params
    if (tid < 64) {
        const int br = tid >> 5, rem = tid & 31, ty = rem >> 4, k = rem & 15;
        const float* p = br ? (ty ? bi1 : Wi1) : (ty ? br1 : Wr1);
        l1w[br][ty][k] = p[f * 16 + k];
    }
    __syncthreads();

    const int lane    = tid & 63;
    const int wv      = tid >> 6;
    const int n       = lane & 31;
    const int half    = lane >> 5;
    const int kb      = half * 8;
    const int wstream = blockIdx.x * 4 + wv;

    float* lw = &lout[wv][0];
    const int s_lo = lane >> 3;   // 0..7: which site of the 8-site store slab
    const int cpos = lane & 7;    // which 16B chunk of the site's 128B line

    for (int t = 0; t < GPW; ++t) {
        const int g    = wstream * GPW + t;
        const int site = g * 32 + n;
        const float2 xv = *(const float2*)(x + ((size_t)site * Fd + f) * 2);

        // ---- L1 (K=1, on VALU), directly in B-fragment layout ----
        uint4 b1h[2], b1l[2];
#pragma unroll
        for (int br = 0; br < 2; ++br) {
            const float xs = br ? xv.y : xv.x;
            const f32x2v xp = {xs, xs};
            f32x2v h[4];
#pragma unroll
            for (int j = 0; j < 4; ++j) {
                f32x2v wv2 = *(const f32x2v*)&l1w[br][0][kb + 2*j];
                f32x2v bv2 = *(const f32x2v*)&l1w[br][1][kb + 2*j];
                h[j] = gelu2(vfma2(xp, wv2, bv2));
            }
            uint4 hv, lv;
            split_pk(h[0].x, h[0].y, hv.x, lv.x);
            split_pk(h[1].x, h[1].y, hv.y, lv.y);
            split_pk(h[2].x, h[2].y, hv.z, lv.z);
            split_pk(h[3].x, h[3].y, hv.w, lv.w);
            b1h[br] = hv; b1l[br] = lv;
        }

        // ---- L2: 16 -> 32, gelu ----
        f32x16 cr = bias_acc(lbias[0], half);
        f32x16 ci = bias_acc(lbias[1], half);
        cr = mfma3(&lfrag[0][0], lane, b1h[0], b1l[0], cr);
        ci = mfma3(&lfrag[2][0], lane, b1h[1], b1l[1], ci);
        gelu16(cr); gelu16(ci);
        uint4 b2h[2][2], b2l[2][2];
        transform_cd(cr, b2h[0], b2l[0]);
        transform_cd(ci, b2h[1], b2l[1]);

        // ---- L3: 32 -> 32, linear ----
        f32x16 ro = bias_acc(lbias[2], half);
        f32x16 io = bias_acc(lbias[3], half);
        ro = mfma3(&lfrag[4][0],  lane, b2h[0][0], b2l[0][0], ro);
        ro = mfma3(&lfrag[6][0],  lane, b2h[0][1], b2l[0][1], ro);
        io = mfma3(&lfrag[8][0],  lane, b2h[1][0], b2l[1][0], io);
        io = mfma3(&lfrag[10][0], lane, b2h[1][1], b2l[1][1], io);
        uint4 fh[4], fl[4];
        transform_cd(ro, &fh[0], &fl[0]);   // F1 k = 0..31
        transform_cd(io, &fh[2], &fl[2]);   // F1 k = 32..63

        // ---- F1: 64 -> 32, gelu ----
        f32x16 c1 = bias_acc(lbias[4], half);
        c1 = mfma3(&lfrag[12][0], lane, fh[0], fl[0], c1);
        c1 = mfma3(&lfrag[14][0], lane, fh[1], fl[1], c1);
        c1 = mfma3(&lfrag[16][0], lane, fh[2], fl[2], c1);
        c1 = mfma3(&lfrag[18][0], lane, fh[3], fl[3], c1);
        gelu16(c1);
        uint4 gh[2], gl[2];
        transform_cd(c1, gh, gl);

        // ---- F2: 32 -> 32, gelu ----
        f32x16 c2 = bias_acc(lbias[5], half);
        c2 = mfma3(&lfrag[20][0], lane, gh[0], gl[0], c2);
        c2 = mfma3(&lfrag[22][0], lane, gh[1], gl[1], c2);
        gelu16(c2);

        // ---- store: stage through a 16-site per-wave LDS tile (two rounds),
        // then write FULL 128B lines (8 lanes x 16B per site). Keeps the
        // no-RMW property of R1 while halving LDS so 4 blocks/CU fit. ----
        // register layout: lane holds site n, feats {4*half + 8q + e}.
#pragma unroll
        for (int r = 0; r < 2; ++r) {
            if ((n >> 4) == r) {
                const int nl = n & 15;
#pragma unroll
                for (int q = 0; q < 4; ++q) {
                    *(float4*)(lw + nl * OTS + q * 8 + 4 * half) =
                        make_float4(c2[4*q+0], c2[4*q+1], c2[4*q+2], c2[4*q+3]);
                }
            }
            // within-wave LDS write->read: drain LDS queue, fence compiler reorder
            asm volatile("s_waitcnt lgkmcnt(0)" ::: "memory");
            __builtin_amdgcn_sched_barrier(0);
#pragma unroll
            for (int it = 0; it < 2; ++it) {
                const int sl    = it * 8 + s_lo;               // 0..15 in tile
                const int gsite = g * 32 + r * 16 + sl;
                float4 v = *(const float4*)(lw + sl * OTS + cpos * 4);
                *(float4*)(out + ((size_t)gsite * Fd + f) * 32 + cpos * 4) = v;
            }
            // reads of this round must retire before next round overwrites tile
            asm volatile("s_waitcnt lgkmcnt(0)" ::: "memory");
            __builtin_amdgcn_sched_barrier(0);
        }
    }
}

} // anonymous namespace

extern "C" void kernel_launch(void* const* d_in, const int* in_sizes, int n_in,
                              void* d_out, int out_size, void* d_ws, size_t ws_size,
                              hipStream_t stream)
{
    const float* x   = (const float*)d_in[0];
    const float* Wr1 = (const float*)d_in[1];
    const float* br1 = (const float*)d_in[2];
    const float* Wr2 = (const float*)d_in[3];
    const float* br2 = (const float*)d_in[4];
    const float* Wr3 = (const float*)d_in[5];
    const float* br3 = (const float*)d_in[6];
    const float* Wi1 = (const float*)d_in[7];
    const float* bi1 = (const float*)d_in[8];
    const float* Wi2 = (const float*)d_in[9];
    const float* bi2 = (const float*)d_in[10];
    const float* Wi3 = (const float*)d_in[11];
    const float* bi3 = (const float*)d_in[12];
    const float* Wf1 = (const float*)d_in[13];
    const float* bf1 = (const float*)d_in[14];
    const float* Wf2 = (const float*)d_in[15];
    const float* bf2 = (const float*)d_in[16];
    float* out = (float*)d_out;

    dim3 grid(GX, Fd, 1);
    dim3 block(256, 1, 1);
    hipLaunchKernelGGL(dcp_mfma_kernel, grid, block, 0, stream,
                       x, Wr1, br1, Wr2, br2, Wr3, br3,
                       Wi1, bi1, Wi2, bi2, Wi3, bi3,
                       Wf1, bf1, Wf2, bf2, out);
}

// Round 8
// 353.285 us; speedup vs baseline: 1.0115x; 1.0115x over previous
//
#include <hip/hip_runtime.h>

namespace {

constexpr int P    = 361;
constexpr int Fd   = 20;
constexpr int BPc  = 256 * P;        // 92416 sites
constexpr int NG   = BPc / 32;       // 2888 site-groups per f
constexpr int GPW  = 8;              // groups per wave-stream
constexpr int NSTR = NG / GPW;       // 361 wave-streams per f
constexpr int GX   = (NSTR + 3) / 4; // 91 blocks.x (4 waves/block, last partial)

constexpr int OTS = 36;              // out-tile row stride in floats (144B, 16B-aligned)

typedef __bf16 bf16x8 __attribute__((ext_vector_type(8)));
typedef __bf16 bf16x2 __attribute__((ext_vector_type(2)));
typedef float  f32x2v __attribute__((ext_vector_type(2)));
typedef float  f32x16 __attribute__((ext_vector_type(16)));

// native <2 x float> fma (correct whether or not backend packs it).
// NOTE: hand-written v_pk_*_f32 inline asm corrupted data in two separate
// attempts (R3: absmax 1.7e-2, R7: NaN) — do NOT reintroduce it.
__device__ __forceinline__ f32x2v vfma2(f32x2v a, f32x2v b, f32x2v c) {
    return __builtin_elementwise_fma(a, b, c);
}

// tanh-form GELU, k2 = 2*log2(e) folded into poly constants:
//   w  = x*(k0m + k1m*x^2)
//   r  = 1/(exp2(w) + 1)            (= 0.5*(1-tanh(y)))
//   g  = x - x*r = fma(-x, r, x)
// Saturates exactly: exp2->inf => r=0 => g=x ; exp2->0 => r=1 => g=0.
__device__ __forceinline__ f32x2v gelu2(f32x2v x) {
    const f32x2v k1m = {0.10294324f, 0.10294324f};   // c0*c1*2log2e
    const f32x2v k0m = {2.3022082f,  2.3022082f};    // c0*2log2e
    const f32x2v one = {1.0f, 1.0f};
    f32x2v x2 = x * x;
    f32x2v p  = vfma2(x2, k1m, k0m);
    f32x2v w  = x * p;
    f32x2v e;
    e.x = __builtin_amdgcn_exp2f(w.x);
    e.y = __builtin_amdgcn_exp2f(w.y);
    f32x2v d = e + one;
    f32x2v r;
    r.x = __builtin_amdgcn_rcpf(d.x);
    r.y = __builtin_amdgcn_rcpf(d.y);
    return vfma2(-x, r, x);
}

// (v0,v1) -> packed hi-bf16 word + packed lo-bf16 word, RNE, via v_cvt_pk_bf16_f32
__device__ __forceinline__ void split_pk(float v0, float v1, unsigned& hw, unsigned& lw) {
    f32x2v vv = {v0, v1};
    bf16x2 hv = __builtin_convertvector(vv, bf16x2);
    unsigned hp = __builtin_bit_cast(unsigned, hv);
    float r0 = __builtin_bit_cast(float, hp << 16);
    float r1 = __builtin_bit_cast(float, hp & 0xffff0000u);
    f32x2v rv = {v0 - r0, v1 - r1};
    bf16x2 lv = __builtin_convertvector(rv, bf16x2);
    hw = hp;
    lw = __builtin_bit_cast(unsigned, lv);
}

__device__ __forceinline__ bf16x8 as_bf8(uint4 u) {
    return __builtin_bit_cast(bf16x8, u);
}

// 3-MFMA bf16x3 product: acc += A * B with A = (ah+al) from LDS frags,
// B = (bh+bl) in registers. Drops al*bl (~2^-18 rel).
__device__ __forceinline__ f32x16 mfma3(const uint4* lf, int lane,
                                        uint4 bh, uint4 bl, f32x16 acc) {
    bf16x8 ah = as_bf8(lf[lane]);
    bf16x8 al = as_bf8(lf[64 + lane]);
    acc = __builtin_amdgcn_mfma_f32_32x32x16_bf16(ah, as_bf8(bh), acc, 0, 0, 0);
    acc = __builtin_amdgcn_mfma_f32_32x32x16_bf16(ah, as_bf8(bl), acc, 0, 0, 0);
    acc = __builtin_amdgcn_mfma_f32_32x32x16_bf16(al, as_bf8(bh), acc, 0, 0, 0);
    return acc;
}

// read per-lane bias (accumulator init) from LDS: layout [half*16 + q*4 + e]
// holds bias[row = e + 8q + 4*half], matching C/D row = (r&3)+8*(r>>2)+4*half.
__device__ __forceinline__ f32x16 bias_acc(const float* lb, int half) {
    f32x16 a;
    const float4* p = (const float4*)(lb + half * 16);
#pragma unroll
    for (int q = 0; q < 4; ++q) {
        float4 v = p[q];
        a[4*q+0] = v.x; a[4*q+1] = v.y; a[4*q+2] = v.z; a[4*q+3] = v.w;
    }
    return a;
}

__device__ __forceinline__ void gelu16(f32x16& c) {
#pragma unroll
    for (int i = 0; i < 8; ++i) {
        f32x2v p = {c[2*i], c[2*i+1]};
        p = gelu2(p);
        c[2*i] = p.x; c[2*i+1] = p.y;
    }
}

// C/D-layout (32 feats x 32 sites) -> two B-fragments (k=0..15, k=16..31),
// hi+lo bf16. C/D: lane holds col n=lane&31, rows (r&3)+8*(r>>2)+4*half.
// B-frag: lane holds n=lane&31, k=(lane>>5)*8+j.
// The half exchange is exactly v_permlane32_swap:
//   swap(A,B): A' = {A_lo, B_lo}, B' = {A_hi, B_hi}
//   v.x,v.z = swap(d[4c+0], d[4c+2]); v.y,v.w = swap(d[4c+1], d[4c+3]).
__device__ __forceinline__ void transform_cd(const f32x16 c, uint4* H, uint4* L) {
    unsigned hd[8], ld[8];
#pragma unroll
    for (int q = 0; q < 4; ++q) {
        split_pk(c[4*q+0], c[4*q+1], hd[2*q],   ld[2*q]);
        split_pk(c[4*q+2], c[4*q+3], hd[2*q+1], ld[2*q+1]);
    }
#pragma unroll
    for (int pr = 0; pr < 2; ++pr) {
        unsigned* d = pr ? ld : hd;
#pragma unroll
        for (int cix = 0; cix < 2; ++cix) {
            unsigned a0 = d[4*cix+0], b0 = d[4*cix+2];
            unsigned a1 = d[4*cix+1], b1 = d[4*cix+3];
            asm("v_permlane32_swap_b32 %0, %1" : "+v"(a0), "+v"(b0));
            asm("v_permlane32_swap_b32 %0, %1" : "+v"(a1), "+v"(b1));
            uint4 v;
            v.x = a0; v.y = a1; v.z = b0; v.w = b1;
            (pr ? L : H)[cix] = v;
        }
    }
}

__global__ __launch_bounds__(256, 4) void dcp_mfma_kernel(
    const float* __restrict__ x,
    const float* __restrict__ Wr1, const float* __restrict__ br1,
    const float* __restrict__ Wr2, const float* __restrict__ br2,
    const float* __restrict__ Wr3, const float* __restrict__ br3,
    const float* __restrict__ Wi1, const float* __restrict__ bi1,
    const float* __restrict__ Wi2, const float* __restrict__ bi2,
    const float* __restrict__ Wi3, const float* __restrict__ bi3,
    const float* __restrict__ Wf1, const float* __restrict__ bf1,
    const float* __restrict__ Wf2, const float* __restrict__ bf2,
    float* __restrict__ out)
{
    // 12 weight A-chunks x {hi,lo}: frag fi=2*chunk+prec, per-lane uint4.
    __shared__ uint4 lfrag[24][64];                 // 24576 B
    __shared__ __align__(16) float lbias[6][32];    //   768 B
    __shared__ __align__(16) float l1w[2][2][16];   //   256 B
    // per-wave out-staging tile: 16 sites x 32 feats, row stride OTS floats
    __shared__ __align__(16) float lout[4][16 * OTS]; // 9216 B  => total 34816 B (4 blocks/CU)

    const int f   = blockIdx.y;
    const int tid = threadIdx.x;

    // ---------- setup: stage weight A-fragments (bf16 hi/lo) into LDS ----------
    // A[m][k] = W[f][k0+k][m]; lane l: m=l&31, k=(l>>5)*8+j.
    for (int s = tid; s < 12 * 64; s += 256) {
        const int chunk = s >> 6;
        const int l     = s & 63;
        const int m     = l & 31;
        const int kb    = (l >> 5) * 8;
        const float* base; int k0;
        switch (chunk) {
            case 0:  base = Wr2 + f * 512;  k0 = 0;  break;
            case 1:  base = Wi2 + f * 512;  k0 = 0;  break;
            case 2:  base = Wr3 + f * 1024; k0 = 0;  break;
            case 3:  base = Wr3 + f * 1024; k0 = 16; break;
            case 4:  base = Wi3 + f * 1024; k0 = 0;  break;
            case 5:  base = Wi3 + f * 1024; k0 = 16; break;
            case 6:  base = Wf1 + f * 2048; k0 = 0;  break;
            case 7:  base = Wf1 + f * 2048; k0 = 16; break;
            case 8:  base = Wf1 + f * 2048; k0 = 32; break;
            case 9:  base = Wf1 + f * 2048; k0 = 48; break;
            case 10: base = Wf2 + f * 1024; k0 = 0;  break;
            default: base = Wf2 + f * 1024; k0 = 16; break;
        }
        uint4 hv, lv;
        split_pk(base[(k0 + kb + 0) * 32 + m], base[(k0 + kb + 1) * 32 + m], hv.x, lv.x);
        split_pk(base[(k0 + kb + 2) * 32 + m], base[(k0 + kb + 3) * 32 + m], hv.y, lv.y);
        split_pk(base[(k0 + kb + 4) * 32 + m], base[(k0 + kb + 5) * 32 + m], hv.z, lv.z);
        split_pk(base[(k0 + kb + 6) * 32 + m], base[(k0 + kb + 7) * 32 + m], hv.w, lv.w);
        lfrag[2 * chunk + 0][l] = hv;
        lfrag[2 * chunk + 1][l] = lv;
    }
    // biases, rearranged to C/D reg order per lane-half
    if (tid < 192) {
        const int set = tid >> 5, i = tid & 31;
        const int row = (i & 3) + 8 * ((i >> 2) & 3) + 4 * (i >> 4);
        const float* bp;
        switch (set) {
            case 0: bp = br2; break; case 1: bp = bi2; break;
            case 2: bp = br3; break; case 3: bp = bi3; break;
            case 4: bp = bf1; break; default: bp = bf2; break;
        }
        lbias[set][i] = bp[f * 32 + row];
    }
    // layer-1 params
    if (tid < 64) {
        const int br = tid >> 5, rem = tid & 31, ty = rem >> 4, k = rem & 15;
        const float* p = br ? (ty ? bi1 : Wi1) : (ty ? br1 : Wr1);
        l1w[br][ty][k] = p[f * 16 + k];
    }
    __syncthreads();

    const int lane    = tid & 63;
    const int wv      = tid >> 6;
    const int n       = lane & 31;
    const int half    = lane >> 5;
    const int kb      = half * 8;
    const int wstream = blockIdx.x * 4 + wv;

    float* lw = &lout[wv][0];
    const int s_lo = lane >> 3;   // 0..7: which site of the 8-site store slab
    const int cpos = lane & 7;    // which 16B chunk of the site's 128B line

    if (wstream < NSTR) {
    for (int t = 0; t < GPW; ++t) {
        const int g    = wstream * GPW + t;
        const int site = g * 32 + n;
        const float2 xv = *(const float2*)(x + ((size_t)site * Fd + f) * 2);

        // ---- L1 (K=1, on VALU), directly in B-fragment layout ----
        uint4 b1h[2], b1l[2];
#pragma unroll
        for (int br = 0; br < 2; ++br) {
            const float xs = br ? xv.y : xv.x;
            const f32x2v xp = {xs, xs};
            f32x2v h[4];
#pragma unroll
            for (int j = 0; j < 4; ++j) {
                f32x2v wv2 = *(const f32x2v*)&l1w[br][0][kb + 2*j];
                f32x2v bv2 = *(const f32x2v*)&l1w[br][1][kb + 2*j];
                h[j] = gelu2(vfma2(xp, wv2, bv2));
            }
            uint4 hv, lv;
            split_pk(h[0].x, h[0].y, hv.x, lv.x);
            split_pk(h[1].x, h[1].y, hv.y, lv.y);
            split_pk(h[2].x, h[2].y, hv.z, lv.z);
            split_pk(h[3].x, h[3].y, hv.w, lv.w);
            b1h[br] = hv; b1l[br] = lv;
        }

        // ---- L2: 16 -> 32, gelu ----
        f32x16 cr = bias_acc(lbias[0], half);
        f32x16 ci = bias_acc(lbias[1], half);
        cr = mfma3(&lfrag[0][0], lane, b1h[0], b1l[0], cr);
        ci = mfma3(&lfrag[2][0], lane, b1h[1], b1l[1], ci);
        gelu16(cr); gelu16(ci);
        uint4 b2h[2][2], b2l[2][2];
        transform_cd(cr, b2h[0], b2l[0]);
        transform_cd(ci, b2h[1], b2l[1]);

        // ---- L3: 32 -> 32, linear ----
        f32x16 ro = bias_acc(lbias[2], half);
        f32x16 io = bias_acc(lbias[3], half);
        ro = mfma3(&lfrag[4][0],  lane, b2h[0][0], b2l[0][0], ro);
        ro = mfma3(&lfrag[6][0],  lane, b2h[0][1], b2l[0][1], ro);
        io = mfma3(&lfrag[8][0],  lane, b2h[1][0], b2l[1][0], io);
        io = mfma3(&lfrag[10][0], lane, b2h[1][1], b2l[1][1], io);
        uint4 fh[4], fl[4];
        transform_cd(ro, &fh[0], &fl[0]);   // F1 k = 0..31
        transform_cd(io, &fh[2], &fl[2]);   // F1 k = 32..63

        // ---- F1: 64 -> 32, gelu ----
        f32x16 c1 = bias_acc(lbias[4], half);
        c1 = mfma3(&lfrag[12][0], lane, fh[0], fl[0], c1);
        c1 = mfma3(&lfrag[14][0], lane, fh[1], fl[1], c1);
        c1 = mfma3(&lfrag[16][0], lane, fh[2], fl[2], c1);
        c1 = mfma3(&lfrag[18][0], lane, fh[3], fl[3], c1);
        gelu16(c1);
        uint4 gh[2], gl[2];
        transform_cd(c1, gh, gl);

        // ---- F2: 32 -> 32, gelu ----
        f32x16 c2 = bias_acc(lbias[5], half);
        c2 = mfma3(&lfrag[20][0], lane, gh[0], gl[0], c2);
        c2 = mfma3(&lfrag[22][0], lane, gh[1], gl[1], c2);
        gelu16(c2);

        // ---- store: stage through a 16-site per-wave LDS tile (two rounds),
        // then write FULL 128B lines (8 lanes x 16B per site). Keeps the
        // no-RMW property while fitting 4 blocks/CU. ----
        // register layout: lane holds site n, feats {4*half + 8q + e}.
#pragma unroll
        for (int r = 0; r < 2; ++r) {
            if ((n >> 4) == r) {
                const int nl = n & 15;
#pragma unroll
                for (int q = 0; q < 4; ++q) {
                    *(float4*)(lw + nl * OTS + q * 8 + 4 * half) =
                        make_float4(c2[4*q+0], c2[4*q+1], c2[4*q+2], c2[4*q+3]);
                }
            }
            // within-wave LDS write->read: drain LDS queue, fence compiler reorder
            asm volatile("s_waitcnt lgkmcnt(0)" ::: "memory");
            __builtin_amdgcn_sched_barrier(0);
#pragma unroll
            for (int it = 0; it < 2; ++it) {
                const int sl    = it * 8 + s_lo;               // 0..15 in tile
                const int gsite = g * 32 + r * 16 + sl;
                float4 v = *(const float4*)(lw + sl * OTS + cpos * 4);
                *(float4*)(out + ((size_t)gsite * Fd + f) * 32 + cpos * 4) = v;
            }
            // reads of this round must retire before next round overwrites tile
            asm volatile("s_waitcnt lgkmcnt(0)" ::: "memory");
            __builtin_amdgcn_sched_barrier(0);
        }
    }
    }
}

} // anonymous namespace

extern "C" void kernel_launch(void* const* d_in, const int* in_sizes, int n_in,
                              void* d_out, int out_size, void* d_ws, size_t ws_size,
                              hipStream_t stream)
{
    const float* x   = (const float*)d_in[0];
    const float* Wr1 = (const float*)d_in[1];
    const float* br1 = (const float*)d_in[2];
    const float* Wr2 = (const float*)d_in[3];
    const float* br2 = (const float*)d_in[4];
    const float* Wr3 = (const float*)d_in[5];
    const float* br3 = (const float*)d_in[6];
    const float* Wi1 = (const float*)d_in[7];
    const float* bi1 = (const float*)d_in[8];
    const float* Wi2 = (const float*)d_in[9];
    const float* bi2 = (const float*)d_in[10];
    const float* Wi3 = (const float*)d_in[11];
    const float* bi3 = (const float*)d_in[12];
    const float* Wf1 = (const float*)d_in[13];
    const float* bf1 = (const float*)d_in[14];
    const float* Wf2 = (const float*)d_in[15];
    const float* bf2 = (const float*)d_in[16];
    float* out = (float*)d_out;

    dim3 grid(GX, Fd, 1);
    dim3 block(256, 1, 1);
    hipLaunchKernelGGL(dcp_mfma_kernel, grid, block, 0, stream,
                       x, Wr1, br1, Wr2, br2, Wr3, br3,
                       Wi1, bi1, Wi2, bi2, Wi3, bi3,
                       Wf1, bf1, Wf2, bf2, out);
}